// Round 10
// baseline (295.053 us; speedup 1.0000x reference)
//
#include <hip/hip_runtime.h>
#include <math.h>

#define B_ 8
#define N_ 2048
#define C_ 512
#define K_ 8
#define EPS 1e-6f
#define GENO_RATIO 0.1f

typedef __bf16 bf16x8 __attribute__((ext_vector_type(8)));
typedef float f32x4 __attribute__((ext_vector_type(4)));

__device__ __forceinline__ ushort f2bf(float x) {
    unsigned int u = __float_as_uint(x);
    u += 0x7fffu + ((u >> 16) & 1u);   // RNE (inputs are finite)
    return (ushort)(u >> 16);
}

// ---------------------------------------------------------------------------
// ws layout (float element offsets):
// [64,128)             cnt (int)   [B,K]
// [128,192)            mass        [B,K]
// [192,32960)          hsum        [B,K,C]    (tpi overlays hsum[0:16384))
// [32960,65728)        ctmp        [B,K,C]    (tpw overlays all of ctmp)
// [65728,196800)       lw          [B,K,N]
// [196800,327872)      ln (int)    [B,K,N]
// [327872,1376448)     w1t2 (bf16) [K][16 cb][512 n][32 cc]   4 MB  (K-tiled)
// [1376448,5570752)    tb2  (bf16) [B][16 cb][2048 n][32 cc]  16.8 MB
// ---------------------------------------------------------------------------

// fused: gating (+geno, + bf16 K-tiled token copy) for blocks [0,4096);
// w1 transpose+convert for blocks [4096,4608).
__global__ __launch_bounds__(256) void k_prep(const float* __restrict__ tokens,
                                              const float* __restrict__ gate_w,
                                              const float* __restrict__ gate_b,
                                              const float* __restrict__ geno_vec,
                                              const float* __restrict__ geno_w,
                                              const float* __restrict__ geno_b,
                                              const float* __restrict__ w1,
                                              int* __restrict__ tpi,
                                              float2* __restrict__ tpw,
                                              ushort* __restrict__ tb2,
                                              ushort* __restrict__ w1t2) {
    __shared__ float smem[8192];   // 32 KB, shared by both bodies
    int tid = threadIdx.x;
    if (blockIdx.x < 4096) {
        float* gwT = smem;          // [8][512] gate_w transposed
        float* qwT = smem + 4096;   // [8][512] geno_w transposed
        for (int i = tid; i < 1024; i += 256) {
            int c = i >> 1, j0 = (i & 1) * 4;
            float4 v = *(const float4*)(gate_w + i * 4);
            gwT[(j0 + 0) * 512 + c] = v.x; gwT[(j0 + 1) * 512 + c] = v.y;
            gwT[(j0 + 2) * 512 + c] = v.z; gwT[(j0 + 3) * 512 + c] = v.w;
            float4 u = *(const float4*)(geno_w + i * 4);
            qwT[(j0 + 0) * 512 + c] = u.x; qwT[(j0 + 1) * 512 + c] = u.y;
            qwT[(j0 + 2) * 512 + c] = u.z; qwT[(j0 + 3) * 512 + c] = u.w;
        }
        __syncthreads();

        int wave = tid >> 6, lane = tid & 63;
        int t = blockIdx.x * 4 + wave;
        int b = t >> 11;
        int n = t & 2047;
        int c0 = lane * 8;
        const float* trow = tokens + (size_t)t * C_;
        float4 v0 = *(const float4*)(trow + c0);
        float4 v1 = *(const float4*)(trow + c0 + 4);
        const float* grow = geno_vec + (size_t)b * C_;
        float4 gy0 = *(const float4*)(grow + c0);
        float4 gy1 = *(const float4*)(grow + c0 + 4);
        float tv[8] = {v0.x, v0.y, v0.z, v0.w, v1.x, v1.y, v1.z, v1.w};
        float gv[8] = {gy0.x, gy0.y, gy0.z, gy0.w, gy1.x, gy1.y, gy1.z, gy1.w};

        float acc[8];
        #pragma unroll
        for (int j = 0; j < 8; ++j) {
            const float* wj = gwT + j * 512 + c0;
            const float* qj = qwT + j * 512 + c0;
            float4 w0 = *(const float4*)(wj);
            float4 w1v = *(const float4*)(wj + 4);
            float4 q0 = *(const float4*)(qj);
            float4 q1 = *(const float4*)(qj + 4);
            float a = 0.f, g = 0.f;
            a = fmaf(tv[0], w0.x, a); a = fmaf(tv[1], w0.y, a);
            a = fmaf(tv[2], w0.z, a); a = fmaf(tv[3], w0.w, a);
            a = fmaf(tv[4], w1v.x, a); a = fmaf(tv[5], w1v.y, a);
            a = fmaf(tv[6], w1v.z, a); a = fmaf(tv[7], w1v.w, a);
            g = fmaf(gv[0], q0.x, g); g = fmaf(gv[1], q0.y, g);
            g = fmaf(gv[2], q0.z, g); g = fmaf(gv[3], q0.w, g);
            g = fmaf(gv[4], q1.x, g); g = fmaf(gv[5], q1.y, g);
            g = fmaf(gv[6], q1.z, g); g = fmaf(gv[7], q1.w, g);
            acc[j] = fmaf(GENO_RATIO, g, a);
        }
        {
            int cb = c0 >> 5, cc = c0 & 31;
            uint4 o;
            o.x = (unsigned)f2bf(tv[0]) | ((unsigned)f2bf(tv[1]) << 16);
            o.y = (unsigned)f2bf(tv[2]) | ((unsigned)f2bf(tv[3]) << 16);
            o.z = (unsigned)f2bf(tv[4]) | ((unsigned)f2bf(tv[5]) << 16);
            o.w = (unsigned)f2bf(tv[6]) | ((unsigned)f2bf(tv[7]) << 16);
            *(uint4*)(tb2 + ((size_t)(b * 16 + cb) * 2048 + n) * 32 + cc) = o;
        }
        #pragma unroll
        for (int off = 32; off > 0; off >>= 1) {
            #pragma unroll
            for (int j = 0; j < 8; ++j) acc[j] += __shfl_xor(acc[j], off, 64);
        }
        if (lane == 0) {
            float lg[8];
            #pragma unroll
            for (int j = 0; j < 8; ++j)
                lg[j] = acc[j] + gate_b[j] + GENO_RATIO * geno_b[j];
            int i0 = 0; float v0m = lg[0];
            #pragma unroll
            for (int j = 1; j < 8; ++j) if (lg[j] > v0m) { v0m = lg[j]; i0 = j; }
            int i1 = -1; float v1m = -1e30f;
            #pragma unroll
            for (int j = 0; j < 8; ++j) if (j != i0 && lg[j] > v1m) { v1m = lg[j]; i1 = j; }
            float e = expf(v1m - v0m);
            float w0 = 1.f / (1.f + e);
            float w1s = e / (1.f + e);
            w0 = fmaxf(w0, EPS); w1s = fmaxf(w1s, EPS);
            float s = w0 + w1s; w0 /= s; w1s /= s;
            tpi[t] = i0 | (i1 << 4);
            tpw[t] = make_float2(w0, w1s);
        }
    } else {
        // w1 transpose+convert: w1t2[k][cb][n][cc] = bf16(w1[k][cb*32+cc][n])
        int id2 = blockIdx.x - 4096;
        int k = id2 >> 6;
        int c0 = ((id2 >> 3) & 7) * 64;
        int n0 = (id2 & 7) * 64;
        float (*tile)[65] = (float(*)[65])smem;
        int tr = tid >> 4;          // 0..15
        int tc4 = (tid & 15) * 4;   // 0..60
        const float* src = w1 + (size_t)k * C_ * C_;
        #pragma unroll
        for (int i = 0; i < 4; ++i) {
            int c = c0 + tr + i * 16;
            float4 v = *(const float4*)(src + (size_t)c * C_ + n0 + tc4);
            tile[tr + i * 16][tc4 + 0] = v.x; tile[tr + i * 16][tc4 + 1] = v.y;
            tile[tr + i * 16][tc4 + 2] = v.z; tile[tr + i * 16][tc4 + 3] = v.w;
        }
        __syncthreads();
        #pragma unroll
        for (int i = 0; i < 4; ++i) {
            int rr = tr + i * 16;
            int n = n0 + rr;
            int c = c0 + tc4;
            int cb = c >> 5, cc = c & 31;
            uint2 o;
            o.x = (unsigned)f2bf(tile[tc4 + 0][rr]) | ((unsigned)f2bf(tile[tc4 + 1][rr]) << 16);
            o.y = (unsigned)f2bf(tile[tc4 + 2][rr]) | ((unsigned)f2bf(tile[tc4 + 3][rr]) << 16);
            *(uint2*)(w1t2 + ((size_t)(k * 16 + cb) * 512 + n) * 32 + cc) = o;
        }
    }
}

// list build + zero hsum/ctmp. One block per batch b; ballot-aggregated LDS
// atomics; reads its own tpi/tpw slice, syncs, then zeroes overlaid regions.
__global__ __launch_bounds__(1024) void k_build(const int* __restrict__ tpi,
                                                const float2* __restrict__ tpw,
                                                int* __restrict__ cnt,
                                                float* __restrict__ mass,
                                                int* __restrict__ ln,
                                                float* __restrict__ lw,
                                                float* __restrict__ hsum,
                                                float* __restrict__ ctmp) {
    int b = blockIdx.x;
    __shared__ int   lcnt[8];
    __shared__ float lmass[8];
    int tid = threadIdx.x;
    if (tid < 8) { lcnt[tid] = 0; lmass[tid] = 0.f; }

    int pk[2]; float2 w[2];
    #pragma unroll
    for (int it = 0; it < 2; ++it) {
        int n = it * 1024 + tid;
        pk[it] = tpi[b * N_ + n];
        w[it]  = tpw[b * N_ + n];
    }
    __syncthreads();

    {
        float4 z = {0.f, 0.f, 0.f, 0.f};
        float4* h4 = (float4*)hsum;
        if (tid < 512) h4[b * 512 + tid] = z;
        else           h4[4096 + b * 512 + (tid - 512)] = z;
        float4* c4 = (float4*)ctmp;
        c4[b * 1024 + tid] = z;
    }

    int lane = tid & 63;
    unsigned long long lt = (1ull << lane) - 1ull;
    #pragma unroll
    for (int it = 0; it < 2; ++it) {
        int n = it * 1024 + tid;
        int i0 = pk[it] & 15, i1 = pk[it] >> 4;
        #pragma unroll
        for (int kk = 0; kk < 8; ++kk) {
            unsigned long long m0 = __ballot(i0 == kk);
            unsigned long long m1 = __ballot(i1 == kk);
            int c0 = __popcll(m0), c1 = __popcll(m1);
            int base = 0;
            if (lane == 0 && (c0 + c1) > 0) base = atomicAdd(&lcnt[kk], c0 + c1);
            base = __shfl(base, 0, 64);
            int pbase = (b * 8 + kk) * N_;
            if (i0 == kk) {
                int pos = base + __popcll(m0 & lt);
                ln[pbase + pos] = n; lw[pbase + pos] = w[it].x;
            }
            if (i1 == kk) {
                int pos = base + c0 + __popcll(m1 & lt);
                ln[pbase + pos] = n; lw[pbase + pos] = w[it].y;
            }
            float s = (i0 == kk ? w[it].x : 0.f) + (i1 == kk ? w[it].y : 0.f);
            #pragma unroll
            for (int off = 32; off > 0; off >>= 1) s += __shfl_xor(s, off, 64);
            if (lane == 0 && s != 0.f) atomicAdd(&lmass[kk], s);
        }
    }
    __syncthreads();
    if (tid < 8) {
        cnt[b * 8 + tid]  = lcnt[tid];
        mass[b * 8 + tid] = lmass[tid];
    }
}

// grouped GEMM1, MFMA bf16. Block = 512 threads (8 waves), tile 128 tokens x
// 512 channels, BK=32. B staged in LDS once per iter (contiguous 32 KB slab
// of K-tiled w1t2, shared by all waves -> B L2/L3 stream halved); A gathered
// rows also LDS-staged. Double-buffered, 1 barrier/iter. Grid 1-D:
// id = b + 8*(m + 16*k): b->XCD (tb2 slice L2-resident), k slowest (only ~2
// expert slabs live per XCD -> w1t2 L2-resident too).
__global__ __launch_bounds__(512, 1) void k_ffn1(const ushort* __restrict__ tb2,
                                                 const ushort* __restrict__ w1t2,
                                                 const float* __restrict__ b1,
                                                 const int* __restrict__ cnt,
                                                 const int* __restrict__ ln,
                                                 const float* __restrict__ lw,
                                                 float* __restrict__ hsum) {
    int id = blockIdx.x;
    int b = id & 7, m = (id >> 3) & 15, k = id >> 7;
    int p = b * 8 + k;
    int count = cnt[p];
    int m0 = m * 128;
    if (m0 >= count) return;

    __shared__ ushort Bs[2][512 * 36];   // 72 KB: 512 ch x 32 bf16, stride 36
    __shared__ ushort As[2][128 * 36];   // 18 KB: 128 tok x 32 bf16, stride 36
    __shared__ int   ns_s[128];
    __shared__ float wls_s[128];

    int tid = threadIdx.x;
    if (tid < 128) {
        int mi = m0 + tid;
        bool v = mi < count;
        ns_s[tid]  = v ? ln[p * N_ + mi] : 0;
        wls_s[tid] = v ? lw[p * N_ + mi] : 0.f;
    }
    __syncthreads();

    int wv = tid >> 6, lane = tid & 63;
    int ln15 = lane & 15, q = lane >> 4;
    int wm = wv & 1, wc = wv >> 1;   // token-half (0..1), channel-quarter (0..3)

    // A staging: thread handles row r = tid>>2 (0..127), 16B piece q4 = tid&3
    int r = tid >> 2, q4 = tid & 3;
    const ushort* agbase = tb2 + ((size_t)(b * 16) * 2048 + ns_s[r]) * 32 + q4 * 8;
    // B staging: the cb-slab w1t2[k][cb] is 512*32 bf16 contiguous = 2048 uint4
    const ushort* bgbase = w1t2 + (size_t)(k * 16) * 512 * 32;

    f32x4 acc[4][8];
    #pragma unroll
    for (int mt = 0; mt < 4; ++mt)
        #pragma unroll
        for (int j = 0; j < 8; ++j) acc[mt][j] = (f32x4){0.f, 0.f, 0.f, 0.f};

    // prologue: stage chunk 0
    {
        uint4 av = *(const uint4*)(agbase);
        *(uint4*)&As[0][r * 36 + q4 * 8] = av;
        #pragma unroll
        for (int i = 0; i < 4; ++i) {
            int idx = tid + i * 512;   // uint4 index within the 32 KB slab
            uint4 bv = *(const uint4*)(bgbase + (size_t)idx * 8);
            *(uint4*)&Bs[0][(idx >> 2) * 36 + (idx & 3) * 8] = bv;
        }
    }
    __syncthreads();

    #pragma unroll 1
    for (int cb = 0; cb < 16; ++cb) {
        uint4 a_nx; uint4 b_nx[4];
        if (cb < 15) {
            a_nx = *(const uint4*)(agbase + (size_t)(cb + 1) * 65536);
            const ushort* bsl = bgbase + (size_t)(cb + 1) * 16384;
            #pragma unroll
            for (int i = 0; i < 4; ++i)
                b_nx[i] = *(const uint4*)(bsl + (size_t)(tid + i * 512) * 8);
        }
        const ushort* ab = &As[cb & 1][0];
        const ushort* bb = &Bs[cb & 1][0];
        bf16x8 afrag[4], bfrag[8];
        #pragma unroll
        for (int mt = 0; mt < 4; ++mt)
            afrag[mt] = *(const bf16x8*)(ab + (wm * 64 + mt * 16 + ln15) * 36 + q * 8);
        #pragma unroll
        for (int j = 0; j < 8; ++j)
            bfrag[j] = *(const bf16x8*)(bb + (wc * 128 + j * 16 + ln15) * 36 + q * 8);
        #pragma unroll
        for (int mt = 0; mt < 4; ++mt)
            #pragma unroll
            for (int j = 0; j < 8; ++j)
                acc[mt][j] = __builtin_amdgcn_mfma_f32_16x16x32_bf16(
                    afrag[mt], bfrag[j], acc[mt][j], 0, 0, 0);
        if (cb < 15) {
            int bn = (cb + 1) & 1;
            *(uint4*)&As[bn][r * 36 + q4 * 8] = a_nx;
            #pragma unroll
            for (int i = 0; i < 4; ++i) {
                int idx = tid + i * 512;
                *(uint4*)&Bs[bn][(idx >> 2) * 36 + (idx & 3) * 8] = b_nx[i];
            }
        }
        __syncthreads();
    }

    // epilogue: bias+relu+gate-weight; reduce 4 q-lanes; 1 atomic per column
    float wrow[4][4];
    #pragma unroll
    for (int mt = 0; mt < 4; ++mt)
        #pragma unroll
        for (int rr = 0; rr < 4; ++rr)
            wrow[mt][rr] = wls_s[wm * 64 + mt * 16 + q * 4 + rr];
    const float* b1k = b1 + k * C_;
    float* hp = hsum + (size_t)p * C_;
    #pragma unroll
    for (int j = 0; j < 8; ++j) {
        int n = wc * 128 + j * 16 + ln15;
        float bias = b1k[n];
        float s = 0.f;
        #pragma unroll
        for (int mt = 0; mt < 4; ++mt)
            #pragma unroll
            for (int rr = 0; rr < 4; ++rr)
                s += wrow[mt][rr] * fmaxf(acc[mt][j][rr] + bias, 0.f);
        s += __shfl_xor(s, 16, 64);
        s += __shfl_xor(s, 32, 64);
        if (q == 0) atomicAdd(&hp[n], s);
    }
}

// combine partials: ctmp[b,k,e] += sum_{c in 64-chunk} hsum[b,k,c]*w2[k,c,e]
__global__ __launch_bounds__(256) void k_comb(const float* __restrict__ hsum,
                                              const float* __restrict__ w2,
                                              float* __restrict__ ctmp) {
    int et = blockIdx.x, k = blockIdx.y, cc = blockIdx.z;
    int e0 = et * 64, c0 = cc * 64;
    __shared__ float hs[8][64];
    int t = threadIdx.x;
    for (int i = t; i < 512; i += 256) {
        int b = i >> 6, c = i & 63;
        hs[b][c] = hsum[(size_t)((b * 8 + k) << 9) + c0 + c];
    }
    __syncthreads();
    int e = e0 + (t & 63); int g = t >> 6;
    float a0 = 0.f, a1 = 0.f;
    const float* w2p = w2 + (size_t)k * C_ * C_ + e;
    #pragma unroll 4
    for (int c = 0; c < 64; ++c) {
        float wv = w2p[(size_t)(c0 + c) * C_];
        a0 = fmaf(hs[g][c], wv, a0);
        a1 = fmaf(hs[g + 4][c], wv, a1);
    }
    atomicAdd(&ctmp[((g * 8 + k) << 9) + e], a0);
    atomicAdd(&ctmp[(((g + 4) * 8 + k) << 9) + e], a1);
}

// finalize: centers = (ctmp + b2*mass)/max(mass,eps); thread0 writes lb_loss
__global__ __launch_bounds__(256) void k_fin(const float* __restrict__ ctmp,
                                             const float* __restrict__ b2,
                                             const float* __restrict__ mass,
                                             const int* __restrict__ cnt,
                                             float* __restrict__ out) {
    int i = blockIdx.x * 256 + threadIdx.x;  // 0..32767
    int b = i >> 12; int ke = i & 4095; int k = ke >> 9;
    float m = mass[b * 8 + k];
    out[i] = (ctmp[i] + b2[ke] * m) / fmaxf(m, EPS);
    if (i == 0) {
        float u[8]; float s = 0.f;
        for (int kk = 0; kk < 8; ++kk) {
            int ck = 0;
            for (int bb = 0; bb < 8; ++bb) ck += cnt[bb * K_ + kk];
            u[kk] = (float)ck / (float)(B_ * N_);
            s += u[kk];
        }
        float mean = s / 8.f;
        float var = 0.f;
        for (int kk = 0; kk < 8; ++kk) { float d = u[kk] - mean; var += d * d; }
        var /= 8.f;
        float denom = mean + EPS;
        out[B_ * K_ * C_] = var / (denom * denom);
    }
}

extern "C" void kernel_launch(void* const* d_in, const int* in_sizes, int n_in,
                              void* d_out, int out_size, void* d_ws, size_t ws_size,
                              hipStream_t stream) {
    (void)in_sizes; (void)n_in; (void)out_size; (void)ws_size;
    const float* tokens   = (const float*)d_in[0];
    const float* geno_vec = (const float*)d_in[1];
    const float* gate_w   = (const float*)d_in[2];
    const float* gate_b   = (const float*)d_in[3];
    const float* geno_w   = (const float*)d_in[4];
    const float* geno_b   = (const float*)d_in[5];
    const float* w1       = (const float*)d_in[6];
    const float* b1       = (const float*)d_in[7];
    const float* w2       = (const float*)d_in[8];
    const float* b2       = (const float*)d_in[9];
    float* out = (float*)d_out;
    float* ws  = (float*)d_ws;

    int*    cnt      = (int*)(ws + 64);          // 64
    float*  mass     = ws + 128;                 // 64
    float*  hsum     = ws + 192;                 // 32768
    float*  ctmp     = ws + 32960;               // 32768
    float*  lw       = ws + 65728;               // 131072
    int*    ln       = (int*)(ws + 196800);      // 131072
    ushort* w1t2     = (ushort*)(ws + 327872);   // 2,097,152 bf16 (4 MB)
    ushort* tb2      = (ushort*)(ws + 1376448);  // 8,388,608 bf16 (16.8 MB)
    int*    tpi      = (int*)hsum;               // overlay, resolved in k_build
    float2* tpw      = (float2*)ctmp;            // overlay, resolved in k_build

    k_prep<<<dim3(4096 + 512), dim3(256), 0, stream>>>(tokens, gate_w, gate_b,
                                                       geno_vec, geno_w, geno_b,
                                                       w1, tpi, tpw, tb2, w1t2);
    k_build<<<dim3(B_), dim3(1024), 0, stream>>>(tpi, tpw, cnt, mass, ln, lw,
                                                 hsum, ctmp);
    k_ffn1<<<dim3(B_ * K_ * (N_ / 128)), dim3(512), 0, stream>>>(tb2, w1t2, b1,
                                                                 cnt, ln, lw, hsum);
    k_comb<<<dim3(8, K_, 8), dim3(256), 0, stream>>>(hsum, w2, ctmp);
    k_fin<<<dim3(128), dim3(256), 0, stream>>>(ctmp, b2, mass, cnt, out);
}

// Round 11
// 194.987 us; speedup vs baseline: 1.5132x; 1.5132x over previous
//
#include <hip/hip_runtime.h>
#include <math.h>

#define B_ 8
#define N_ 2048
#define C_ 512
#define K_ 8
#define EPS 1e-6f
#define GENO_RATIO 0.1f

typedef __bf16 bf16x8 __attribute__((ext_vector_type(8)));
typedef float f32x4 __attribute__((ext_vector_type(4)));

__device__ __forceinline__ ushort f2bf(float x) {
    unsigned int u = __float_as_uint(x);
    u += 0x7fffu + ((u >> 16) & 1u);   // RNE (inputs are finite)
    return (ushort)(u >> 16);
}

// ---------------------------------------------------------------------------
// ws layout (float element offsets):
// [64,128)             cnt (int)   [B,K]
// [128,192)            mass        [B,K]
// [192,32960)          hsum        [B,K,C]
// [32960,65728)        ctmp        [B,K,C]
// [65728,196800)       lw          [B,K,N]
// [196800,327872)      ln (int)    [B,K,N]
// [327872,1376448)     w1t2 (bf16) [K][16 cb][512 n][32 cc]   4 MB  (K-tiled)
// [1376448,5570752)    tb2  (bf16) [B][16 cb][2048 n][32 cc]  16.8 MB
// ---------------------------------------------------------------------------

// k_prep: w1 transpose+convert (512 blocks) + zero cnt/mass/hsum/ctmp.
__global__ __launch_bounds__(256) void k_prep(const float* __restrict__ w1,
                                              ushort* __restrict__ w1t2,
                                              float* __restrict__ zws) {
    int id2 = blockIdx.x;
    int tid = threadIdx.x;
    // zero hsum+ctmp (65536 floats = 16384 float4, 32 per block); block 0
    // additionally zeroes cnt+mass (128 floats = 32 float4).
    {
        float4 z = {0.f, 0.f, 0.f, 0.f};
        float4* h4 = (float4*)(zws + 128);     // hsum start (ws+192)
        if (tid < 32) h4[id2 * 32 + tid] = z;
        if (id2 == 0 && tid >= 32 && tid < 64) ((float4*)zws)[tid - 32] = z;
    }
    // transpose: w1t2[k][cb][n][cc] = bf16(w1[k][cb*32+cc][n])
    __shared__ float tile[64][65];
    int k = id2 >> 6;
    int c0 = ((id2 >> 3) & 7) * 64;
    int n0 = (id2 & 7) * 64;
    int tr = tid >> 4;          // 0..15
    int tc4 = (tid & 15) * 4;   // 0..60
    const float* src = w1 + (size_t)k * C_ * C_;
    #pragma unroll
    for (int i = 0; i < 4; ++i) {
        int c = c0 + tr + i * 16;
        float4 v = *(const float4*)(src + (size_t)c * C_ + n0 + tc4);
        tile[tr + i * 16][tc4 + 0] = v.x; tile[tr + i * 16][tc4 + 1] = v.y;
        tile[tr + i * 16][tc4 + 2] = v.z; tile[tr + i * 16][tc4 + 3] = v.w;
    }
    __syncthreads();
    #pragma unroll
    for (int i = 0; i < 4; ++i) {
        int rr = tr + i * 16;
        int n = n0 + rr;
        int c = c0 + tc4;
        int cb = c >> 5, cc = c & 31;
        uint2 o;
        o.x = (unsigned)f2bf(tile[tc4 + 0][rr]) | ((unsigned)f2bf(tile[tc4 + 1][rr]) << 16);
        o.y = (unsigned)f2bf(tile[tc4 + 2][rr]) | ((unsigned)f2bf(tile[tc4 + 3][rr]) << 16);
        *(uint2*)(w1t2 + ((size_t)(k * 16 + cb) * 512 + n) * 32 + cc) = o;
    }
}

// k_gate: gating + bf16 token copy + fused list build.
// Block = 256 thr = 4 waves, 64 tokens of one batch (wave wv: tokens
// wv*16..wv*16+15). Lane owns channels {lane+64i} (stride-64: conflict-free,
// coalesced). Gate weights in VGPRs (loaded once); geno bias once per wave.
// List build: wave 0 ballots over the 64-token window, one global atomicAdd
// per (block, expert) to reserve list ranges (cnt pre-zeroed by k_prep).
__global__ __launch_bounds__(256, 2) void k_gate(const float* __restrict__ tokens,
                                                 const float* __restrict__ gate_w,
                                                 const float* __restrict__ gate_b,
                                                 const float* __restrict__ geno_vec,
                                                 const float* __restrict__ geno_w,
                                                 const float* __restrict__ geno_b,
                                                 int* __restrict__ cnt,
                                                 float* __restrict__ mass,
                                                 int* __restrict__ ln,
                                                 float* __restrict__ lw,
                                                 ushort* __restrict__ tb2) {
    __shared__ int    pks[64];
    __shared__ float2 wts[64];
    int tid = threadIdx.x;
    int wv = tid >> 6, lane = tid & 63;
    int b  = blockIdx.x >> 5;
    int n0 = (blockIdx.x & 31) * 64;
    int p_row = b * 8;

    // preload gate weights: rows c = lane+64i, 8 floats each (2 x float4)
    const float4* gw4 = (const float4*)gate_w;
    float4 gwa[8], gwb[8];
    #pragma unroll
    for (int i = 0; i < 8; ++i) {
        int c = lane + 64 * i;
        gwa[i] = gw4[c * 2];
        gwb[i] = gw4[c * 2 + 1];
    }
    // geno logits once (depend only on b)
    float ga[8] = {0.f,0.f,0.f,0.f,0.f,0.f,0.f,0.f};
    {
        const float* grow = geno_vec + (size_t)b * C_;
        const float4* qw4 = (const float4*)geno_w;
        #pragma unroll
        for (int i = 0; i < 8; ++i) {
            int c = lane + 64 * i;
            float gv = grow[c];
            float4 q0 = qw4[c * 2], q1 = qw4[c * 2 + 1];
            ga[0] = fmaf(gv, q0.x, ga[0]); ga[1] = fmaf(gv, q0.y, ga[1]);
            ga[2] = fmaf(gv, q0.z, ga[2]); ga[3] = fmaf(gv, q0.w, ga[3]);
            ga[4] = fmaf(gv, q1.x, ga[4]); ga[5] = fmaf(gv, q1.y, ga[5]);
            ga[6] = fmaf(gv, q1.z, ga[6]); ga[7] = fmaf(gv, q1.w, ga[7]);
        }
        #pragma unroll
        for (int off = 32; off > 0; off >>= 1) {
            #pragma unroll
            for (int j = 0; j < 8; ++j) ga[j] += __shfl_xor(ga[j], off, 64);
        }
    }
    float gbias[8];
    #pragma unroll
    for (int j = 0; j < 8; ++j)
        gbias[j] = gate_b[j] + GENO_RATIO * (ga[j] + geno_b[j]);

    // token loop with distance-1 prefetch of the next token row
    const float* tb = tokens + ((size_t)(b * N_ + n0 + wv * 16)) * C_ + lane;
    float tv[8];
    #pragma unroll
    for (int i = 0; i < 8; ++i) tv[i] = tb[64 * i];
    #pragma unroll 1
    for (int it = 0; it < 16; ++it) {
        float tn[8];
        if (it < 15) {
            const float* tr2 = tb + (size_t)(it + 1) * C_;
            #pragma unroll
            for (int i = 0; i < 8; ++i) tn[i] = tr2[64 * i];
        }
        int n = n0 + wv * 16 + it;
        float acc[8] = {0.f,0.f,0.f,0.f,0.f,0.f,0.f,0.f};
        #pragma unroll
        for (int i = 0; i < 8; ++i) {
            acc[0] = fmaf(tv[i], gwa[i].x, acc[0]);
            acc[1] = fmaf(tv[i], gwa[i].y, acc[1]);
            acc[2] = fmaf(tv[i], gwa[i].z, acc[2]);
            acc[3] = fmaf(tv[i], gwa[i].w, acc[3]);
            acc[4] = fmaf(tv[i], gwb[i].x, acc[4]);
            acc[5] = fmaf(tv[i], gwb[i].y, acc[5]);
            acc[6] = fmaf(tv[i], gwb[i].z, acc[6]);
            acc[7] = fmaf(tv[i], gwb[i].w, acc[7]);
        }
        // bf16 K-tiled store: channel c = lane+64i -> cb=(lane>>5)+2i, cc=lane&31
        {
            int cc = lane & 31, cbb = lane >> 5;
            ushort* tp = tb2 + ((size_t)(b * 16 + cbb) * 2048 + n) * 32 + cc;
            #pragma unroll
            for (int i = 0; i < 8; ++i)
                tp[(size_t)(2 * i) * 65536] = f2bf(tv[i]);
        }
        #pragma unroll
        for (int off = 32; off > 0; off >>= 1) {
            #pragma unroll
            for (int j = 0; j < 8; ++j) acc[j] += __shfl_xor(acc[j], off, 64);
        }
        if (lane == 0) {
            float lg[8];
            #pragma unroll
            for (int j = 0; j < 8; ++j) lg[j] = acc[j] + gbias[j];
            int i0 = 0; float v0m = lg[0];
            #pragma unroll
            for (int j = 1; j < 8; ++j) if (lg[j] > v0m) { v0m = lg[j]; i0 = j; }
            int i1 = -1; float v1m = -1e30f;
            #pragma unroll
            for (int j = 0; j < 8; ++j) if (j != i0 && lg[j] > v1m) { v1m = lg[j]; i1 = j; }
            float e = expf(v1m - v0m);
            float w0 = 1.f / (1.f + e);
            float w1s = e / (1.f + e);
            w0 = fmaxf(w0, EPS); w1s = fmaxf(w1s, EPS);
            float s = w0 + w1s; w0 /= s; w1s /= s;
            pks[wv * 16 + it] = i0 | (i1 << 4);
            wts[wv * 16 + it] = make_float2(w0, w1s);
        }
        #pragma unroll
        for (int i = 0; i < 8; ++i) tv[i] = tn[i];
    }
    __syncthreads();

    // list build: wave 0, one lane per token of the window
    if (tid < 64) {
        int pk = pks[lane];
        float2 w = wts[lane];
        int n = n0 + lane;
        int i0 = pk & 15, i1 = pk >> 4;
        unsigned long long lt = (1ull << lane) - 1ull;
        #pragma unroll
        for (int kk = 0; kk < 8; ++kk) {
            unsigned long long m0 = __ballot(i0 == kk);
            unsigned long long m1 = __ballot(i1 == kk);
            int c0 = __popcll(m0), c1 = __popcll(m1);
            int base = 0;
            if (lane == 0 && (c0 + c1) > 0) base = atomicAdd(&cnt[p_row + kk], c0 + c1);
            base = __shfl(base, 0, 64);
            int pbase = (p_row + kk) * N_;
            if (i0 == kk) {
                int pos = base + __popcll(m0 & lt);
                ln[pbase + pos] = n; lw[pbase + pos] = w.x;
            }
            if (i1 == kk) {
                int pos = base + c0 + __popcll(m1 & lt);
                ln[pbase + pos] = n; lw[pbase + pos] = w.y;
            }
            float s = (i0 == kk ? w.x : 0.f) + (i1 == kk ? w.y : 0.f);
            #pragma unroll
            for (int off = 32; off > 0; off >>= 1) s += __shfl_xor(s, off, 64);
            if (lane == 0 && s != 0.f) atomicAdd(&mass[p_row + kk], s);
        }
    }
}

// grouped GEMM1, MFMA bf16 (R9-exact, measured 54.7 us). 1-D XCD-affine grid:
// id = b + 8*(k + 8*m). Wave owns 128 ch (32 MFMA per 8 loads). A: LDS dbuf
// staged (runtime loop, 1 barrier/iter); B: loop-carried VGPR dbuf.
__global__ __launch_bounds__(256, 2) void k_ffn1(const ushort* __restrict__ tb2,
                                                 const ushort* __restrict__ w1t2,
                                                 const float* __restrict__ b1,
                                                 const int* __restrict__ cnt,
                                                 const int* __restrict__ ln,
                                                 const float* __restrict__ lw,
                                                 float* __restrict__ hsum) {
    int id = blockIdx.x;
    int b = id & 7, k = (id >> 3) & 7, m = id >> 6;
    int p = b * 8 + k;
    int count = cnt[p];
    int m0 = m * 64;
    if (m0 >= count) return;

    __shared__ ushort As[2][64 * 34];   // 64 rows x 32 bf16, stride 34 (68B)
    __shared__ int   ns_s[64];
    __shared__ float wls_s[64];
    int tid = threadIdx.x;
    if (tid < 64) {
        int mi = m0 + tid;
        bool v = mi < count;
        ns_s[tid]  = v ? ln[p * N_ + mi] : 0;
        wls_s[tid] = v ? lw[p * N_ + mi] : 0.f;
    }
    __syncthreads();

    int wv = tid >> 6, lane = tid & 63;
    int ln15 = lane & 15, q = lane >> 4;

    int r = tid >> 2, q4 = tid & 3;
    const ushort* agbase = tb2 + ((size_t)(b * 16) * 2048 + ns_s[r]) * 32 + q4 * 8;
    const ushort* bb0 = w1t2 + ((size_t)(k * 16) * 512 + wv * 128 + ln15) * 32 + q * 8;

    f32x4 acc[4][8];
    #pragma unroll
    for (int mt = 0; mt < 4; ++mt)
        #pragma unroll
        for (int j = 0; j < 8; ++j) acc[mt][j] = (f32x4){0.f, 0.f, 0.f, 0.f};

    uint4 b_cur[8], b_nxt[8];
    {
        uint4 av = *(const uint4*)(agbase);
        *(uint4*)&As[0][r * 34 + q4 * 8] = av;
    }
    #pragma unroll
    for (int j = 0; j < 8; ++j) b_cur[j] = *(const uint4*)(bb0 + j * 512);
    __syncthreads();

    #pragma unroll 1
    for (int cb = 0; cb < 16; ++cb) {
        uint4 a_nx;
        if (cb < 15) {
            a_nx = *(const uint4*)(agbase + (size_t)(cb + 1) * 65536);
            #pragma unroll
            for (int j = 0; j < 8; ++j)
                b_nxt[j] = *(const uint4*)(bb0 + (size_t)(cb + 1) * 16384 + j * 512);
        }
        const ushort* ab = &As[cb & 1][0];
        bf16x8 afrag[4];
        #pragma unroll
        for (int mt = 0; mt < 4; ++mt)
            afrag[mt] = *(const bf16x8*)(ab + (mt * 16 + ln15) * 34 + q * 8);
        union { uint4 u; bf16x8 v; } bc;
        #pragma unroll
        for (int mt = 0; mt < 4; ++mt)
            #pragma unroll
            for (int j = 0; j < 8; ++j) {
                bc.u = b_cur[j];
                acc[mt][j] = __builtin_amdgcn_mfma_f32_16x16x32_bf16(
                    afrag[mt], bc.v, acc[mt][j], 0, 0, 0);
            }
        if (cb < 15) {
            *(uint4*)&As[(cb + 1) & 1][r * 34 + q4 * 8] = a_nx;
            #pragma unroll
            for (int j = 0; j < 8; ++j) b_cur[j] = b_nxt[j];
        }
        __syncthreads();
    }

    float wrow[4][4];
    #pragma unroll
    for (int mt = 0; mt < 4; ++mt)
        #pragma unroll
        for (int rr = 0; rr < 4; ++rr) wrow[mt][rr] = wls_s[mt * 16 + q * 4 + rr];
    const float* b1k = b1 + k * C_;
    float* hp = hsum + (size_t)p * C_;
    #pragma unroll
    for (int j = 0; j < 8; ++j) {
        int n = wv * 128 + j * 16 + ln15;
        float bias = b1k[n];
        float s = 0.f;
        #pragma unroll
        for (int mt = 0; mt < 4; ++mt)
            #pragma unroll
            for (int rr = 0; rr < 4; ++rr)
                s += wrow[mt][rr] * fmaxf(acc[mt][j][rr] + bias, 0.f);
        s += __shfl_xor(s, 16, 64);
        s += __shfl_xor(s, 32, 64);
        if (q == 0) atomicAdd(&hp[n], s);
    }
}

// combine partials: ctmp[b,k,e] += sum_{c in 64-chunk} hsum[b,k,c]*w2[k,c,e]
__global__ __launch_bounds__(256) void k_comb(const float* __restrict__ hsum,
                                              const float* __restrict__ w2,
                                              float* __restrict__ ctmp) {
    int et = blockIdx.x, k = blockIdx.y, cc = blockIdx.z;
    int e0 = et * 64, c0 = cc * 64;
    __shared__ float hs[8][64];
    int t = threadIdx.x;
    for (int i = t; i < 512; i += 256) {
        int b = i >> 6, c = i & 63;
        hs[b][c] = hsum[(size_t)((b * 8 + k) << 9) + c0 + c];
    }
    __syncthreads();
    int e = e0 + (t & 63); int g = t >> 6;
    float a0 = 0.f, a1 = 0.f;
    const float* w2p = w2 + (size_t)k * C_ * C_ + e;
    #pragma unroll 4
    for (int c = 0; c < 64; ++c) {
        float wv = w2p[(size_t)(c0 + c) * C_];
        a0 = fmaf(hs[g][c], wv, a0);
        a1 = fmaf(hs[g + 4][c], wv, a1);
    }
    atomicAdd(&ctmp[((g * 8 + k) << 9) + e], a0);
    atomicAdd(&ctmp[(((g + 4) * 8 + k) << 9) + e], a1);
}

// finalize: centers = (ctmp + b2*mass)/max(mass,eps); thread0 writes lb_loss
__global__ __launch_bounds__(256) void k_fin(const float* __restrict__ ctmp,
                                             const float* __restrict__ b2,
                                             const float* __restrict__ mass,
                                             const int* __restrict__ cnt,
                                             float* __restrict__ out) {
    int i = blockIdx.x * 256 + threadIdx.x;  // 0..32767
    int b = i >> 12; int ke = i & 4095; int k = ke >> 9;
    float m = mass[b * 8 + k];
    out[i] = (ctmp[i] + b2[ke] * m) / fmaxf(m, EPS);
    if (i == 0) {
        float u[8]; float s = 0.f;
        for (int kk = 0; kk < 8; ++kk) {
            int ck = 0;
            for (int bb = 0; bb < 8; ++bb) ck += cnt[bb * K_ + kk];
            u[kk] = (float)ck / (float)(B_ * N_);
            s += u[kk];
        }
        float mean = s / 8.f;
        float var = 0.f;
        for (int kk = 0; kk < 8; ++kk) { float d = u[kk] - mean; var += d * d; }
        var /= 8.f;
        float denom = mean + EPS;
        out[B_ * K_ * C_] = var / (denom * denom);
    }
}

extern "C" void kernel_launch(void* const* d_in, const int* in_sizes, int n_in,
                              void* d_out, int out_size, void* d_ws, size_t ws_size,
                              hipStream_t stream) {
    (void)in_sizes; (void)n_in; (void)out_size; (void)ws_size;
    const float* tokens   = (const float*)d_in[0];
    const float* geno_vec = (const float*)d_in[1];
    const float* gate_w   = (const float*)d_in[2];
    const float* gate_b   = (const float*)d_in[3];
    const float* geno_w   = (const float*)d_in[4];
    const float* geno_b   = (const float*)d_in[5];
    const float* w1       = (const float*)d_in[6];
    const float* b1       = (const float*)d_in[7];
    const float* w2       = (const float*)d_in[8];
    const float* b2       = (const float*)d_in[9];
    float* out = (float*)d_out;
    float* ws  = (float*)d_ws;

    int*    cnt      = (int*)(ws + 64);          // 64
    float*  mass     = ws + 128;                 // 64
    float*  hsum     = ws + 192;                 // 32768
    float*  ctmp     = ws + 32960;               // 32768
    float*  lw       = ws + 65728;               // 131072
    int*    ln       = (int*)(ws + 196800);      // 131072
    ushort* w1t2     = (ushort*)(ws + 327872);   // 2,097,152 bf16 (4 MB)
    ushort* tb2      = (ushort*)(ws + 1376448);  // 8,388,608 bf16 (16.8 MB)

    k_prep<<<dim3(512), dim3(256), 0, stream>>>(w1, w1t2, ws + 64);
    k_gate<<<dim3(B_ * N_ / 64), dim3(256), 0, stream>>>(tokens, gate_w, gate_b,
                                                         geno_vec, geno_w, geno_b,
                                                         cnt, mass, ln, lw, tb2);
    k_ffn1<<<dim3(B_ * K_ * (N_ / 64)), dim3(256), 0, stream>>>(tb2, w1t2, b1,
                                                                cnt, ln, lw, hsum);
    k_comb<<<dim3(8, K_, 8), dim3(256), 0, stream>>>(hsum, w2, ctmp);
    k_fin<<<dim3(128), dim3(256), 0, stream>>>(ctmp, b2, mass, cnt, out);
}